// Round 16
// baseline (335.815 us; speedup 1.0000x reference)
//
#include <hip/hip_runtime.h>
#include <hip/hip_fp16.h>
#include <math.h>

#define NN 200000
#define NE 500000
#define FF 166
#define HH 128
#define CC 2
#define TT 49
#define GG 498            // 3*FF
#define PADN 203136
#define MAXTILES 6400
#define KP 84             // k-pairs (166 -> 84 half2, padded)
#define KPAD 192          // K padded to 6*32 for MFMA
#define SCB 512           // scan elements per block
#define SNB 391           // ceil(NN/512)
#define HB 782            // 256-element histogram chunks
#define CIB 1954          // ceil(NE/256)
#define XSB 37500         // ceil(NN*48/256)
#define NK 392            // sort keys: t*8 + degree-class
// setup1 (512-thread) block ranges
#define P2B 210           // ceil((2*KP*512 + FF*HH)/512)
#define C2B 977           // ceil(NE/512)
#define H2B 391           // ceil(NN/512) hist chunks (in gru dispatch)
// degf_m ranges
#define DEGB 782
#define MBB (TT * 96)     // 4704: 2 rows/block covering KPAD=192 rows

typedef _Float16 half2v __attribute__((ext_vector_type(2)));
typedef _Float16 f16x4 __attribute__((ext_vector_type(4)));
typedef _Float16 f16x8 __attribute__((ext_vector_type(8)));
typedef float f32x4 __attribute__((ext_vector_type(4)));

static __device__ __forceinline__ float fdot2f(half2v a, half2v b, float c) {
#if __has_builtin(__builtin_amdgcn_fdot2)
    return __builtin_amdgcn_fdot2(a, b, c, false);
#else
    return c + (float)a.x * (float)b.x + (float)a.y * (float)b.y;
#endif
}

// ============ setup1: prep_pack ∥ count_indeg+actdeg ============
__global__ __launch_bounds__(512) void setup1(
        const float* __restrict__ wih, const float* __restrict__ whh,
        const float* __restrict__ projw,
        _Float16* __restrict__ wkp, float* __restrict__ projwT,
        const int* __restrict__ srcp, const int* __restrict__ dstp,
        const int* __restrict__ ts,
        int* __restrict__ offc, int* __restrict__ actdeg) {
    int b = blockIdx.x;
    int tid = threadIdx.x;
    if (b < P2B) {
        int idx = b * 512 + tid;
        const int A = 2 * KP * 512;
        if (idx < A) {
            int m = idx / (KP * 512);
            int r = idx - m * (KP * 512);
            int kp = r >> 9, c = r & 511;
            const float* Wm = m ? whh : wih;
            float x0 = 0.0f, x1 = 0.0f;
            if (c < GG) {
                int k0 = 2 * kp, k1 = 2 * kp + 1;
                if (k0 < FF) x0 = Wm[c * FF + k0];
                if (k1 < FF) x1 = Wm[c * FF + k1];
            }
            wkp[2 * idx]     = (_Float16)x0;
            wkp[2 * idx + 1] = (_Float16)x1;
        } else if (idx < A + FF * HH) {
            int q = idx - A;
            int k = q >> 7, hh = q & 127;
            projwT[q] = projw[hh * FF + k];
        }
    } else {
        int e = (b - P2B) * 512 + tid;
        if (e < NE) {
            int d = dstp[e];
            atomicAdd(&offc[d], 1);
            if (ts[srcp[e]] <= ts[d]) atomicAdd(&actdeg[d], 1);
        }
    }
}

// ============ gru_hist: GRU chain (166 blocks) ∥ hist_rank w/ 392 keys ============
__global__ __launch_bounds__(512) void gru_hist(
        const float* __restrict__ initial_w,
        const _Float16* __restrict__ wkp,
        const float* __restrict__ bih, const float* __restrict__ bhh,
        float* __restrict__ W_all,
        const int* __restrict__ ts, const int* __restrict__ actdeg,
        int* __restrict__ cnt, int* __restrict__ rank) {
    __shared__ float s_w[FF];
    __shared__ __align__(16) _Float16 s_wh[2 * KP];
    __shared__ float s_pre[2][512];
    __shared__ int h2[2][NK];
    int tid = threadIdx.x;
    int b = blockIdx.x;

    if (b < FF) {
        int row = b;
        if (tid < FF) {
            float v = initial_w[(size_t)row * FF + tid];
            s_w[tid] = v;
            s_wh[tid] = (_Float16)v;
        } else if (tid < 2 * KP) {
            s_wh[tid] = (_Float16)0.0f;
        }

        int cc0 = tid * 2;
        bool act = cc0 < 996;
        int m = (cc0 >= 498) ? 1 : 0;
        int c0 = act ? (cc0 - m * 498) : 0;

        half2v wr0[KP], wr1[KP];
        {
            const half2v* __restrict__ pW =
                (const half2v*)wkp + (size_t)(act ? m : 0) * (KP * 512) + c0;
            #pragma unroll
            for (int kp = 0; kp < KP; ++kp) {
                wr0[kp] = pW[(size_t)(kp << 9)];
                wr1[kp] = pW[(size_t)(kp << 9) + 1];
            }
        }

        float bi_r = 0, bi_z = 0, bi_n = 0, bh_r = 0, bh_z = 0, bh_n = 0;
        if (tid < FF) {
            bi_r = bih[tid]; bi_z = bih[FF + tid]; bi_n = bih[2 * FF + tid];
            bh_r = bhh[tid]; bh_z = bhh[FF + tid]; bh_n = bhh[2 * FF + tid];
        }
        __syncthreads();

        const f16x8* s_wh8 = (const f16x8*)s_wh;
        for (int t = 0; t < TT; ++t) {
            if (act) {
                float a0 = 0.0f, a1 = 0.0f;
                #pragma unroll
                for (int q = 0; q < 21; ++q) {
                    f16x8 w8 = s_wh8[q];
                    half2v h0 = __builtin_shufflevector(w8, w8, 0, 1);
                    half2v h1 = __builtin_shufflevector(w8, w8, 2, 3);
                    half2v h2v = __builtin_shufflevector(w8, w8, 4, 5);
                    half2v h3 = __builtin_shufflevector(w8, w8, 6, 7);
                    a0 = fdot2f(wr0[4 * q + 0], h0, a0);  a1 = fdot2f(wr1[4 * q + 0], h0, a1);
                    a0 = fdot2f(wr0[4 * q + 1], h1, a0);  a1 = fdot2f(wr1[4 * q + 1], h1, a1);
                    a0 = fdot2f(wr0[4 * q + 2], h2v, a0); a1 = fdot2f(wr1[4 * q + 2], h2v, a1);
                    a0 = fdot2f(wr0[4 * q + 3], h3, a0);  a1 = fdot2f(wr1[4 * q + 3], h3, a1);
                }
                s_pre[m][c0]     = a0;
                s_pre[m][c0 + 1] = a1;
            }
            __syncthreads();
            if (tid < FF) {
                float i_r = s_pre[0][tid]          + bi_r;
                float h_r = s_pre[1][tid]          + bh_r;
                float i_z = s_pre[0][FF + tid]     + bi_z;
                float h_z = s_pre[1][FF + tid]     + bh_z;
                float i_n = s_pre[0][2 * FF + tid] + bi_n;
                float h_n = s_pre[1][2 * FF + tid] + bh_n;
                float rg = 1.0f / (1.0f + expf(-(i_r + h_r)));
                float zg = 1.0f / (1.0f + expf(-(i_z + h_z)));
                float ng = tanhf(i_n + rg * h_n);
                float wnew = (1.0f - zg) * ng + zg * s_w[tid];
                s_w[tid] = wnew;
                s_wh[tid] = (_Float16)wnew;
                W_all[((size_t)t * FF + row) * FF + tid] = wnew;
            }
            __syncthreads();
        }
    } else {
        // -------- hist_rank: key = t*8 + min(actdeg,7), two 256-chunks --------
        int hb2 = b - FF;                 // 0..390
        int sub = tid >> 8;               // 0/1
        int lt = tid & 255;
        for (int k = lt; k < NK; k += 256) h2[sub][k] = 0;
        __syncthreads();
        int i = hb2 * 512 + tid;
        if (i < NN) {
            int ad = actdeg[i];
            int key = ts[i] * 8 + (ad > 7 ? 7 : ad);
            rank[i] = atomicAdd(&h2[sub][key], 1);
        }
        __syncthreads();
        for (int k = lt; k < NK; k += 256) cnt[(size_t)(hb2 * 2 + sub) * NK + k] = h2[sub][k];
    }
}

// ============ setup2: scan_p1 ∥ bucket_scan (392 keys) ============
__global__ __launch_bounds__(256) void setup2(
        const int* __restrict__ off, int* __restrict__ bsum,
        const int* __restrict__ cnt, int* __restrict__ basecol, int* __restrict__ kcnt) {
    __shared__ int s[256];
    int b = blockIdx.x, tid = threadIdx.x;
    if (b < SNB) {
        int i0 = b * SCB + tid * 2;
        int v = 0;
        if (i0 < NN) v += off[i0];
        if (i0 + 1 < NN) v += off[i0 + 1];
        s[tid] = v;
        __syncthreads();
        for (int d = 128; d > 0; d >>= 1) {
            if (tid < d) s[tid] += s[tid + d];
            __syncthreads();
        }
        if (tid == 0) bsum[b] = s[0];
    } else {
        int key = b - SNB;                 // 0..391
        const int CH = (HB + 255) / 256;   // 4
        int b0 = tid * CH;
        int loc[4];
        int sum = 0;
        for (int u = 0; u < CH; ++u) {
            int bb = b0 + u;
            int v = (bb < HB) ? cnt[(size_t)bb * NK + key] : 0;
            loc[u] = sum;
            sum += v;
        }
        s[tid] = sum;
        __syncthreads();
        for (int d = 1; d < 256; d <<= 1) {
            int u = (tid >= d) ? s[tid - d] : 0;
            __syncthreads();
            s[tid] += u;
            __syncthreads();
        }
        int base = s[tid] - sum;
        for (int u = 0; u < CH; ++u) {
            int bb = b0 + u;
            if (bb < HB) basecol[(size_t)bb * NK + key] = base + loc[u];
        }
        if (tid == 255) kcnt[key] = s[255];
    }
}

// ============ setup3: scan_p2 (block 0) ∥ make_tiles+keybase (block 1) ============
__global__ __launch_bounds__(512) void setup3(
        const int* __restrict__ bsum, int* __restrict__ bpre, int* __restrict__ off,
        const int* __restrict__ kcnt, int* __restrict__ keybase, int* __restrict__ pstart,
        int* __restrict__ tile_t, int* __restrict__ tile_r0, int* __restrict__ meta) {
    __shared__ int s[512];
    __shared__ int skc[NK];
    int tid = threadIdx.x;
    if (blockIdx.x == 0) {
        int v = (tid < SNB) ? bsum[tid] : 0;
        s[tid] = v;
        __syncthreads();
        for (int d = 1; d < 512; d <<= 1) {
            int u = (tid >= d) ? s[tid - d] : 0;
            __syncthreads();
            s[tid] += u;
            __syncthreads();
        }
        bpre[tid] = s[tid] - v;
        if (tid == 511) off[NN] = s[511];
    } else {
        for (int k = tid; k < NK; k += 512) skc[k] = kcnt[k];
        __syncthreads();
        int nt = 0;
        if (tid < TT) {
            int base = 0;
            for (int c = 0; c < 8; ++c) {
                keybase[tid * 8 + c] = base;
                base += skc[tid * 8 + c];
            }
            nt = (base + 31) / 32;
        }
        if (tid < 64) s[tid] = nt;
        __syncthreads();
        for (int d = 1; d < 64; d <<= 1) {
            int v = (tid >= d && tid < 64) ? s[tid - d] : 0;
            __syncthreads();
            if (tid < 64) s[tid] += v;
            __syncthreads();
        }
        if (tid < 64) {
            int ntbase = s[tid] - nt;
            int pbase = ntbase * 32;
            if (tid < TT) {
                pstart[tid] = pbase;
                for (int u = 0; u < nt; ++u) {
                    tile_t[ntbase + u] = tid;
                    tile_r0[ntbase + u] = pbase + u * 32;
                }
            }
            if (tid == 63) {
                meta[0] = s[63];
                meta[1] = s[63] * 32;
                pstart[TT] = s[63] * 32;
            }
        }
    }
}

// ============ setup4: scan_p3 ∥ perm_scatter (keyed) ============
__global__ __launch_bounds__(512) void setup4(
        int* __restrict__ off, const int* __restrict__ bpre,
        const int* __restrict__ ts, const int* __restrict__ actdeg,
        const int* __restrict__ rank,
        const int* __restrict__ basecol, const int* __restrict__ keybase,
        const int* __restrict__ pstart,
        int* __restrict__ perm, int* __restrict__ pos) {
    __shared__ int s[512];
    int b = blockIdx.x, tid = threadIdx.x;
    if (b < SNB) {
        int i = b * SCB + tid;
        int v = (i < NN) ? off[i] : 0;
        s[tid] = v;
        __syncthreads();
        for (int d = 1; d < 512; d <<= 1) {
            int u = (tid >= d) ? s[tid - d] : 0;
            __syncthreads();
            s[tid] += u;
            __syncthreads();
        }
        if (i < NN) off[i] = s[tid] - v + bpre[b];
    } else {
        int i = (b - SNB) * 512 + tid;
        if (i < NN) {
            int t = ts[i];
            int ad = actdeg[i];
            int key = t * 8 + (ad > 7 ? 7 : ad);
            int hb = i >> 8;
            int p = pstart[t] + keybase[key] + basecol[(size_t)hb * NK + key] + rank[i];
            perm[p] = i;
            pos[i] = p;
        }
    }
}

// ============ setup5: fill_adj (packed pos+ts) ∥ x_scatter ============
__global__ __launch_bounds__(256) void setup5(
        const int* __restrict__ srcp, const int* __restrict__ dstp,
        const int* __restrict__ ts, const int* __restrict__ off,
        int* __restrict__ cursor, int2* __restrict__ adjst,
        const float* __restrict__ x, const int* __restrict__ pos,
        f16x4* __restrict__ x2p4) {
    int b = blockIdx.x, tid = threadIdx.x;
    if (b < CIB) {
        int e = b * 256 + tid;
        if (e < NE) {
            int d = dstp[e];
            int s2 = srcp[e];
            int p = atomicAdd(&cursor[d], 1);
            adjst[off[d] + p] = make_int2(s2, (ts[s2] << 25) | pos[s2]);
        }
    } else {
        int idx = (b - CIB) * 256 + tid;
        if (idx >= NN * 48) return;
        int i = idx / 48, cp4 = idx - i * 48;
        int c0 = cp4 * 4;
        float v0 = 0.f, v1 = 0.f, v2 = 0.f, v3 = 0.f;
        const float* xr = x + (size_t)i * FF;
        if (c0 + 3 < FF) {
            float2 p0 = *(const float2*)(xr + c0);
            float2 p1 = *(const float2*)(xr + c0 + 2);
            v0 = p0.x; v1 = p0.y; v2 = p1.x; v3 = p1.y;
        } else if (c0 < FF) {   // c0 == 164
            float2 p0 = *(const float2*)(xr + c0);
            v0 = p0.x; v1 = p0.y;
        }
        f16x4 h;
        h[0] = (_Float16)v0; h[1] = (_Float16)v1;
        h[2] = (_Float16)v2; h[3] = (_Float16)v3;
        x2p4[(size_t)pos[i] * 48 + cp4] = h;
    }
}

// ============ degf_m: degf_hist ∥ m_build (256 thr) ============
__global__ __launch_bounds__(256) void degf_m(
        const int* __restrict__ off, const int2* __restrict__ adjst,
        const int* __restrict__ ts, _Float16* __restrict__ dinvh,
        float* __restrict__ selfdeg,
        const float* __restrict__ W_all, const float* __restrict__ projwT,
        _Float16* __restrict__ Mh) {
    __shared__ unsigned short sh[TT * 256];
    __shared__ __align__(16) float sw2[2][168];
    int b = blockIdx.x;
    int tid = threadIdx.x;
    if (b < DEGB) {
        int i = b * 256 + tid;
        for (int t = 0; t < TT; ++t) sh[t * 256 + tid] = 0;
        if (i >= NN) return;
        int tsi = ts[i];
        int e0 = off[i], e1 = off[i + 1];
        for (int e = e0; e < e1; ++e) {
            int tj = adjst[e].y >> 25;
            sh[tj * 256 + tid]++;
        }
        int cum = 1;
        for (int t = 0; t < TT; ++t) {
            cum += sh[t * 256 + tid];
            dinvh[(size_t)t * NN + i] = (_Float16)rsqrtf((float)cum);
            if (t == tsi) selfdeg[i] = 1.0f / (float)cum;
        }
    } else {
        int mb = b - DEGB;                 // 0..4703
        int t = mb / 96, rb = mb - t * 96; // rows r0 = rb*2 (0..190)
        int r0 = rb * 2;
        for (int idx = tid; idx < 2 * FF; idx += 256) {
            int rr = idx / FF, k = idx - rr * FF;
            int r = r0 + rr;
            sw2[rr][k] = (r < FF) ? W_all[((size_t)t * FF + r) * FF + k] : 0.0f;
        }
        __syncthreads();
        int rr = tid >> 7, h = tid & 127;
        int r = r0 + rr;
        float acc = 0.0f;
        if (r < FF) {
            const float* __restrict__ pw = projwT + h;
            #pragma unroll 4
            for (int c4 = 0; c4 < 164; c4 += 4) {
                float4 w = *(const float4*)&sw2[rr][c4];
                acc += w.x * pw[(size_t)(c4 + 0) << 7];
                acc += w.y * pw[(size_t)(c4 + 1) << 7];
                acc += w.z * pw[(size_t)(c4 + 2) << 7];
                acc += w.w * pw[(size_t)(c4 + 3) << 7];
            }
            acc += sw2[rr][164] * pw[(size_t)164 << 7];
            acc += sw2[rr][165] * pw[(size_t)165 << 7];
        }
        Mh[((size_t)t * HH + h) * KPAD + r] = (_Float16)acc;
    }
}

// ============ edge_compact: ewp[off[i]..] = {pos_j, w>0} (pos pre-packed) ============
__global__ __launch_bounds__(256) void edge_compact(
        const int* __restrict__ off, const int2* __restrict__ adjst,
        const int* __restrict__ ts, const _Float16* __restrict__ dinvh,
        int2* __restrict__ ewp, int* __restrict__ nact) {
    int i = blockIdx.x * 256 + threadIdx.x;
    if (i >= NN) return;
    int t = ts[i];
    const _Float16* dv = dinvh + (size_t)t * NN;
    float dvi = (float)dv[i];
    int e0 = off[i], e1 = off[i + 1];
    int c = e0;
    for (int e = e0; e < e1; ++e) {
        int2 a = adjst[e];
        if ((a.y >> 25) <= t) {
            float w = (float)dv[a.x] * dvi;
            ewp[c++] = make_int2(a.y & 0x1FFFFFF, __float_as_int(w));
        }
    }
    nact[i] = c - e0;
}

// ============ fused: staged self + pipelined 4-row/wave edge gather + MFMA + proj + cls ============
__global__ __launch_bounds__(512) void gemm_fused5(
        const int* __restrict__ meta, const int* __restrict__ tile_t,
        const int* __restrict__ tile_r0, const int* __restrict__ perm,
        const float* __restrict__ selfdeg, const f16x4* __restrict__ x2p4,
        const int* __restrict__ off, const int* __restrict__ nact,
        const int2* __restrict__ ewp,
        const _Float16* __restrict__ Mh, const float* __restrict__ proj_b,
        const float* __restrict__ cls_w, const float* __restrict__ cls_b,
        float* __restrict__ out) {
    __shared__ __align__(16) char smraw[32 * 130 * 4];
    _Float16* sY = (_Float16*)smraw;   // [32][200] fp16
    float* sP = (float*)smraw;         // [32][130] f32
    int bid = blockIdx.x;
    if (bid >= meta[0]) return;
    int t = tile_t[bid], r0 = tile_r0[bid];
    int tid = threadIdx.x;
    int lane = tid & 63;
    int w = tid >> 6;          // 8 waves
    bool ln48 = lane < 48;

    // ---- stage x2p tile (32 contiguous rows x 24 uint4 = 12 KB) ----
    {
        const uint4* src = (const uint4*)(x2p4 + (size_t)r0 * 48);
        #pragma unroll
        for (int u = 0; u < 2; ++u) {
            int q = tid + u * 512;
            if (q < 768) {
                int row = q / 24, kc = q - row * 24;
                *(uint4*)(sY + row * 200 + kc * 8) = src[q];
            }
        }
    }
    __syncthreads();

    // ---- phase 0: wave w owns rows w*4..w*4+3 (degree-sorted => near-equal nact) ----
    int rbase = w * 4;
    int ep[4], ee[4];
    float ac[4][4];
    #pragma unroll
    for (int q = 0; q < 4; ++q) {
        int r = rbase + q;
        int i = perm[r0 + r];
        float sw = 0.0f;
        ep[q] = 0; ee[q] = 0;
        if (i >= 0) {
            sw = selfdeg[i];
            ep[q] = off[i];
            ee[q] = ep[q] + nact[i];
        }
        f16x4 h = (f16x4)((_Float16)0.0f);
        if (ln48) h = *(const f16x4*)(sY + r * 200 + lane * 4);
        ac[q][0] = sw * (float)h[0];
        ac[q][1] = sw * (float)h[1];
        ac[q][2] = sw * (float)h[2];
        ac[q][3] = sw * (float)h[3];
    }
    int2 pc[4];
    #pragma unroll
    for (int q = 0; q < 4; ++q) pc[q] = (ep[q] < ee[q]) ? ewp[ep[q]] : make_int2(0, 0);
    while ((ep[0] < ee[0]) | (ep[1] < ee[1]) | (ep[2] < ee[2]) | (ep[3] < ee[3])) {
        int js[4]; float wv[4];
        #pragma unroll
        for (int q = 0; q < 4; ++q) {
            bool val = ep[q] < ee[q];
            js[q] = pc[q].x;
            wv[q] = val ? __int_as_float(pc[q].y) : 0.0f;
            if (val) ep[q]++;
        }
        #pragma unroll
        for (int q = 0; q < 4; ++q) pc[q] = (ep[q] < ee[q]) ? ewp[ep[q]] : make_int2(0, 0);
        #pragma unroll
        for (int q = 0; q < 4; ++q) {
            if (wv[q] != 0.0f && ln48) {
                f16x4 g = x2p4[(size_t)js[q] * 48 + lane];
                ac[q][0] += wv[q] * (float)g[0];
                ac[q][1] += wv[q] * (float)g[1];
                ac[q][2] += wv[q] * (float)g[2];
                ac[q][3] += wv[q] * (float)g[3];
            }
        }
    }
    #pragma unroll
    for (int q = 0; q < 4; ++q) {
        if (ln48) {
            f16x4 o;
            o[0] = (_Float16)ac[q][0];
            o[1] = (_Float16)ac[q][1];
            o[2] = (_Float16)ac[q][2];
            o[3] = (_Float16)ac[q][3];
            *(f16x4*)(sY + (rbase + q) * 200 + lane * 4) = o;
        }
    }
    __syncthreads();

    // ---- phase 1: MFMA. wave w -> 16-col block c0 = w*16 ----
    int lr = lane & 15;
    int kg = lane >> 4;
    int c0 = w * 16;
    f32x4 acc0 = {0, 0, 0, 0}, acc1 = {0, 0, 0, 0};
    const _Float16* B0 = Mh + ((size_t)t * HH + c0 + lr) * KPAD + kg * 8;
    const _Float16* A0 = sY + lr * 200 + kg * 8;
    const _Float16* A1 = A0 + 16 * 200;

    #pragma unroll
    for (int s = 0; s < 6; ++s) {
        f16x8 b0 = *(const f16x8*)(B0 + s * 32);
        f16x8 a0 = *(const f16x8*)(A0 + s * 32);
        f16x8 a1 = *(const f16x8*)(A1 + s * 32);
        acc0 = __builtin_amdgcn_mfma_f32_16x16x32_f16(a0, b0, acc0, 0, 0, 0);
        acc1 = __builtin_amdgcn_mfma_f32_16x16x32_f16(a1, b0, acc1, 0, 0, 0);
    }

    float pb = proj_b[c0 + lr];
    __syncthreads();
    int prow = kg * 4;
    int colw = c0 + lr;
    #pragma unroll
    for (int r = 0; r < 4; ++r) {
        sP[(prow + r) * 130 + colw]      = fmaxf(acc0[r] + pb, 0.0f);
        sP[(16 + prow + r) * 130 + colw] = fmaxf(acc1[r] + pb, 0.0f);
    }
    __syncthreads();

    // ---- phase 2: logits ----
    int row = tid >> 4, cc = (tid >> 3) & 1, qq = tid & 7;
    const float* pr = sP + row * 130 + qq * 16;
    const float* cw = cls_w + cc * HH + qq * 16;
    float s = 0.0f;
    #pragma unroll
    for (int h = 0; h < 16; ++h) s += pr[h] * cw[h];
    s += __shfl_xor(s, 1);
    s += __shfl_xor(s, 2);
    s += __shfl_xor(s, 4);
    if (qq == 0) {
        int node = perm[r0 + row];
        if (node >= 0) out[(size_t)node * CC + cc] = s + cls_b[cc];
    }
}

// ============ host ============
extern "C" void kernel_launch(void* const* d_in, const int* in_sizes, int n_in,
                              void* d_out, int out_size, void* d_ws, size_t ws_size,
                              hipStream_t stream) {
    const float* x = (const float*)d_in[0];
    const int* ei = (const int*)d_in[1];
    const int* srcp = ei;
    const int* dstp = ei + NE;
    const int* ts = (const int*)d_in[2];
    const float* initial_w = (const float*)d_in[3];
    const float* wih = (const float*)d_in[4];
    const float* whh = (const float*)d_in[5];
    const float* bih = (const float*)d_in[6];
    const float* bhh = (const float*)d_in[7];
    const float* projw = (const float*)d_in[8];
    const float* projb = (const float*)d_in[9];
    const float* clsw = (const float*)d_in[10];
    const float* clsb = (const float*)d_in[11];
    float* out = (float*)d_out;

    char* base = (char*)d_ws;
    size_t o = 0;
    auto alloc = [&](size_t bytes) { size_t r = o; o = (o + bytes + 255) & ~(size_t)255; return r; };

    float*    W_all   = (float*)   (base + alloc((size_t)TT * FF * FF * 4));
    _Float16* Mh      = (_Float16*)(base + alloc((size_t)TT * HH * KPAD * 2));
    _Float16* wkp     = (_Float16*)(base + alloc((size_t)2 * KP * 512 * 2 * 2));
    float*    projwT  = (float*)   (base + alloc((size_t)FF * HH * 4));
    int*      off     = (int*)     (base + alloc((size_t)(NN + 1) * 4));
    int*      cursor  = (int*)     (base + alloc((size_t)NN * 4));
    int*      actdeg  = (int*)     (base + alloc((size_t)NN * 4));
    int2*     adjst   = (int2*)    (base + alloc((size_t)NE * 8));
    int2*     ewp     = (int2*)    (base + alloc((size_t)NE * 8));
    _Float16* dinvh   = (_Float16*)(base + alloc((size_t)TT * NN * 2));
    float*    selfdeg = (float*)   (base + alloc((size_t)NN * 4));
    int*      nact    = (int*)     (base + alloc((size_t)NN * 4));
    int*      pos     = (int*)     (base + alloc((size_t)NN * 4));
    int*      kcnt    = (int*)     (base + alloc((size_t)NK * 4));
    int*      keybase = (int*)     (base + alloc((size_t)NK * 4));
    int*      pstart  = (int*)     (base + alloc((size_t)(TT + 1) * 4));
    int*      meta    = (int*)     (base + alloc(2 * 4));
    int*      tile_t  = (int*)     (base + alloc((size_t)MAXTILES * 4));
    int*      tile_r0 = (int*)     (base + alloc((size_t)MAXTILES * 4));
    int*      perm    = (int*)     (base + alloc((size_t)PADN * 4));
    int*      bsum    = (int*)     (base + alloc((size_t)512 * 4));
    int*      bpre    = (int*)     (base + alloc((size_t)520 * 4));
    int*      cnt     = (int*)     (base + alloc((size_t)HB * NK * 4));
    int*      basecol = (int*)     (base + alloc((size_t)HB * NK * 4));
    int*      rank    = (int*)     (base + alloc((size_t)NN * 4));
    f16x4*    x2p4    = (f16x4*)   (base + alloc((size_t)PADN * 48 * 8));

    // off, cursor, actdeg are consecutive allocs: one memset covers all three
    hipMemsetAsync(off, 0, (size_t)((char*)actdeg - (char*)off) + (size_t)NN * 4, stream);
    hipMemsetAsync(perm, 0xFF, (size_t)PADN * 4, stream);

    setup1<<<P2B + C2B, 512, 0, stream>>>(wih, whh, projw, wkp, projwT,
                                          srcp, dstp, ts, off, actdeg);
    gru_hist<<<FF + H2B, 512, 0, stream>>>(initial_w, wkp, bih, bhh, W_all,
                                           ts, actdeg, cnt, rank);
    setup2<<<SNB + NK, 256, 0, stream>>>(off, bsum, cnt, basecol, kcnt);
    setup3<<<2, 512, 0, stream>>>(bsum, bpre, off, kcnt, keybase, pstart, tile_t, tile_r0, meta);
    setup4<<<SNB + SNB, 512, 0, stream>>>(off, bpre, ts, actdeg, rank, basecol, keybase,
                                          pstart, perm, pos);
    setup5<<<CIB + XSB, 256, 0, stream>>>(srcp, dstp, ts, off, cursor, adjst, x, pos, x2p4);
    degf_m<<<DEGB + MBB, 256, 0, stream>>>(off, adjst, ts, dinvh, selfdeg, W_all, projwT, Mh);
    edge_compact<<<(NN + 255) / 256, 256, 0, stream>>>(off, adjst, ts, dinvh, ewp, nact);

    gemm_fused5<<<MAXTILES, 512, 0, stream>>>(meta, tile_t, tile_r0, perm, selfdeg,
                                              x2p4, off, nact, ewp, Mh, projb, clsw, clsb, out);
}

// Round 17
// 319.940 us; speedup vs baseline: 1.0496x; 1.0496x over previous
//
#include <hip/hip_runtime.h>
#include <hip/hip_fp16.h>
#include <math.h>

#define NN 200000
#define NE 500000
#define FF 166
#define HH 128
#define CC 2
#define TT 49
#define GG 498            // 3*FF
#define PADN 203136
#define MAXTILES 6400
#define KP 84             // k-pairs (166 -> 84 half2, padded)
#define KPAD 192          // K padded to 6*32 for MFMA
#define SCB 512           // scan elements per block
#define SNB 391           // ceil(NN/512)
#define HB 782            // 256-element histogram chunks
#define CIB 1954          // ceil(NE/256)
#define XSB 37500         // ceil(NN*48/256)
// setup1 (512-thread) block ranges
#define P2B 210           // ceil((2*KP*512 + FF*HH)/512)
#define C2B 977           // ceil(NE/512)
#define H2B 391           // ceil(NN/512) hist chunks
// degf_m ranges
#define DEGB 782
#define MBB (TT * 96)     // 4704: 2 rows/block covering KPAD=192 rows

typedef _Float16 half2v __attribute__((ext_vector_type(2)));
typedef _Float16 f16x4 __attribute__((ext_vector_type(4)));
typedef _Float16 f16x8 __attribute__((ext_vector_type(8)));
typedef float f32x4 __attribute__((ext_vector_type(4)));

static __device__ __forceinline__ float fdot2f(half2v a, half2v b, float c) {
#if __has_builtin(__builtin_amdgcn_fdot2)
    return __builtin_amdgcn_fdot2(a, b, c, false);
#else
    return c + (float)a.x * (float)b.x + (float)a.y * (float)b.y;
#endif
}

// ============ setup1: prep_pack ∥ count_indeg ∥ hist_rank ============
__global__ __launch_bounds__(512) void setup1(
        const float* __restrict__ wih, const float* __restrict__ whh,
        const float* __restrict__ projw,
        _Float16* __restrict__ wkp, float* __restrict__ projwT,
        const int* __restrict__ dstp, int* __restrict__ offc,
        const int* __restrict__ ts, int* __restrict__ cnt, int* __restrict__ rank) {
    __shared__ int h2[2][TT];
    int b = blockIdx.x;
    int tid = threadIdx.x;
    if (b < P2B) {
        int idx = b * 512 + tid;
        const int A = 2 * KP * 512;
        if (idx < A) {
            int m = idx / (KP * 512);
            int r = idx - m * (KP * 512);
            int kp = r >> 9, c = r & 511;
            const float* Wm = m ? whh : wih;
            float x0 = 0.0f, x1 = 0.0f;
            if (c < GG) {
                int k0 = 2 * kp, k1 = 2 * kp + 1;
                if (k0 < FF) x0 = Wm[c * FF + k0];
                if (k1 < FF) x1 = Wm[c * FF + k1];
            }
            wkp[2 * idx]     = (_Float16)x0;
            wkp[2 * idx + 1] = (_Float16)x1;
        } else if (idx < A + FF * HH) {
            int q = idx - A;
            int k = q >> 7, hh = q & 127;
            projwT[q] = projw[hh * FF + k];
        }
    } else if (b < P2B + C2B) {
        int e = (b - P2B) * 512 + tid;
        if (e < NE) atomicAdd(&offc[dstp[e]], 1);
    } else {
        int hb2 = b - P2B - C2B;                  // 0..390
        int sub = tid >> 8;                       // 0/1
        int lt = tid & 255;
        if (lt < TT) h2[sub][lt] = 0;
        __syncthreads();
        int i = hb2 * 512 + tid;
        if (i < NN) {
            int t = ts[i];
            rank[i] = atomicAdd(&h2[sub][t], 1);
        }
        __syncthreads();
        if (lt < TT) cnt[(hb2 * 2 + sub) * TT + lt] = h2[sub][lt];
    }
}

// ============ setup2g: gru_evolve (166) ∥ scan_p1 (391) ∥ bucket_scan (49) ============
__global__ __launch_bounds__(512) void setup2g(
        const float* __restrict__ initial_w, const _Float16* __restrict__ wkp,
        const float* __restrict__ bih, const float* __restrict__ bhh,
        float* __restrict__ W_all,
        const int* __restrict__ off, int* __restrict__ bsum,
        const int* __restrict__ cnt, int* __restrict__ basecol, int* __restrict__ bcnt) {
    __shared__ float s_w[FF];
    __shared__ __align__(16) _Float16 s_wh[2 * KP];
    __shared__ float s_pre[2][512];
    __shared__ int s[512];
    int tid = threadIdx.x;
    int b = blockIdx.x;

    if (b < FF) {
        // -------- GRU chain: row = b, weights register-resident --------
        int row = b;
        if (tid < FF) {
            float v = initial_w[(size_t)row * FF + tid];
            s_w[tid] = v;
            s_wh[tid] = (_Float16)v;
        } else if (tid < 2 * KP) {
            s_wh[tid] = (_Float16)0.0f;
        }
        int cc0 = tid * 2;
        bool act = cc0 < 996;
        int m = (cc0 >= 498) ? 1 : 0;
        int c0 = act ? (cc0 - m * 498) : 0;
        half2v wr0[KP], wr1[KP];
        {
            const half2v* __restrict__ pW =
                (const half2v*)wkp + (size_t)(act ? m : 0) * (KP * 512) + c0;
            #pragma unroll
            for (int kp = 0; kp < KP; ++kp) {
                wr0[kp] = pW[(size_t)(kp << 9)];
                wr1[kp] = pW[(size_t)(kp << 9) + 1];
            }
        }
        float bi_r = 0, bi_z = 0, bi_n = 0, bh_r = 0, bh_z = 0, bh_n = 0;
        if (tid < FF) {
            bi_r = bih[tid]; bi_z = bih[FF + tid]; bi_n = bih[2 * FF + tid];
            bh_r = bhh[tid]; bh_z = bhh[FF + tid]; bh_n = bhh[2 * FF + tid];
        }
        __syncthreads();
        const f16x8* s_wh8 = (const f16x8*)s_wh;
        for (int t = 0; t < TT; ++t) {
            if (act) {
                float a0 = 0.0f, a1 = 0.0f;
                #pragma unroll
                for (int q = 0; q < 21; ++q) {
                    f16x8 w8 = s_wh8[q];
                    half2v h0 = __builtin_shufflevector(w8, w8, 0, 1);
                    half2v h1 = __builtin_shufflevector(w8, w8, 2, 3);
                    half2v h2v = __builtin_shufflevector(w8, w8, 4, 5);
                    half2v h3 = __builtin_shufflevector(w8, w8, 6, 7);
                    a0 = fdot2f(wr0[4 * q + 0], h0, a0);  a1 = fdot2f(wr1[4 * q + 0], h0, a1);
                    a0 = fdot2f(wr0[4 * q + 1], h1, a0);  a1 = fdot2f(wr1[4 * q + 1], h1, a1);
                    a0 = fdot2f(wr0[4 * q + 2], h2v, a0); a1 = fdot2f(wr1[4 * q + 2], h2v, a1);
                    a0 = fdot2f(wr0[4 * q + 3], h3, a0);  a1 = fdot2f(wr1[4 * q + 3], h3, a1);
                }
                s_pre[m][c0]     = a0;
                s_pre[m][c0 + 1] = a1;
            }
            __syncthreads();
            if (tid < FF) {
                float i_r = s_pre[0][tid]          + bi_r;
                float h_r = s_pre[1][tid]          + bh_r;
                float i_z = s_pre[0][FF + tid]     + bi_z;
                float h_z = s_pre[1][FF + tid]     + bh_z;
                float i_n = s_pre[0][2 * FF + tid] + bi_n;
                float h_n = s_pre[1][2 * FF + tid] + bh_n;
                float rg = 1.0f / (1.0f + expf(-(i_r + h_r)));
                float zg = 1.0f / (1.0f + expf(-(i_z + h_z)));
                float ng = tanhf(i_n + rg * h_n);
                float wnew = (1.0f - zg) * ng + zg * s_w[tid];
                s_w[tid] = wnew;
                s_wh[tid] = (_Float16)wnew;
                W_all[((size_t)t * FF + row) * FF + tid] = wnew;
            }
            __syncthreads();
        }
    } else if (b < FF + SNB) {
        // -------- scan_p1: block sums of off (512 elems/block) --------
        int bb = b - FF;
        int i = bb * SCB + tid;
        s[tid] = (i < NN) ? off[i] : 0;
        __syncthreads();
        for (int d = 256; d > 0; d >>= 1) {
            if (tid < d) s[tid] += s[tid + d];
            __syncthreads();
        }
        if (tid == 0) bsum[bb] = s[0];
    } else {
        // -------- bucket_scan: column scan of cnt over HB chunks --------
        int t = b - FF - SNB;             // 0..48
        int b0 = tid * 2;
        int v0 = (b0 < HB) ? cnt[b0 * TT + t] : 0;
        int v1 = (b0 + 1 < HB) ? cnt[(b0 + 1) * TT + t] : 0;
        int sum = v0 + v1;
        s[tid] = sum;
        __syncthreads();
        for (int d = 1; d < 512; d <<= 1) {
            int u = (tid >= d) ? s[tid - d] : 0;
            __syncthreads();
            s[tid] += u;
            __syncthreads();
        }
        int base = s[tid] - sum;
        if (b0 < HB) basecol[b0 * TT + t] = base;
        if (b0 + 1 < HB) basecol[(b0 + 1) * TT + t] = base + v0;
        if (tid == 511) bcnt[t] = s[511];
    }
}

// ============ setup3: scan_p2 (block 0) ∥ make_tiles (block 1) ============
__global__ __launch_bounds__(512) void setup3(
        const int* __restrict__ bsum, int* __restrict__ bpre, int* __restrict__ off,
        const int* __restrict__ bcnt, int* __restrict__ pstart,
        int* __restrict__ tile_t, int* __restrict__ tile_r0, int* __restrict__ meta) {
    __shared__ int s[512];
    int tid = threadIdx.x;
    if (blockIdx.x == 0) {
        int v = (tid < SNB) ? bsum[tid] : 0;
        s[tid] = v;
        __syncthreads();
        for (int d = 1; d < 512; d <<= 1) {
            int u = (tid >= d) ? s[tid - d] : 0;
            __syncthreads();
            s[tid] += u;
            __syncthreads();
        }
        bpre[tid] = s[tid] - v;
        if (tid == 511) off[NN] = s[511];
    } else {
        int t = tid;
        int nt = (t < TT) ? (bcnt[t] + 31) / 32 : 0;
        if (t < 64) s[t] = nt;
        __syncthreads();
        for (int d = 1; d < 64; d <<= 1) {
            int v = (t >= d && t < 64) ? s[t - d] : 0;
            __syncthreads();
            if (t < 64) s[t] += v;
            __syncthreads();
        }
        if (t < 64) {
            int ntbase = s[t] - nt;
            int pbase = ntbase * 32;
            if (t < TT) {
                pstart[t] = pbase;
                for (int u = 0; u < nt; ++u) {
                    tile_t[ntbase + u] = t;
                    tile_r0[ntbase + u] = pbase + u * 32;
                }
            }
            if (t == 63) {
                meta[0] = s[63];
                meta[1] = s[63] * 32;
                pstart[TT] = s[63] * 32;
            }
        }
    }
}

// ============ setup4: scan_p3 ∥ perm_scatter ============
__global__ __launch_bounds__(512) void setup4(
        int* __restrict__ off, const int* __restrict__ bpre,
        const int* __restrict__ ts, const int* __restrict__ rank,
        const int* __restrict__ basecol, const int* __restrict__ pstart,
        int* __restrict__ perm, int* __restrict__ pos) {
    __shared__ int s[512];
    int b = blockIdx.x, tid = threadIdx.x;
    if (b < SNB) {
        int i = b * SCB + tid;
        int v = (i < NN) ? off[i] : 0;
        s[tid] = v;
        __syncthreads();
        for (int d = 1; d < 512; d <<= 1) {
            int u = (tid >= d) ? s[tid - d] : 0;
            __syncthreads();
            s[tid] += u;
            __syncthreads();
        }
        if (i < NN) off[i] = s[tid] - v + bpre[b];
    } else {
        int i = (b - SNB) * 512 + tid;
        if (i < NN) {
            int t = ts[i];
            int hb = i >> 8;
            int p = pstart[t] + basecol[hb * TT + t] + rank[i];
            perm[p] = i;
            pos[i] = p;
        }
    }
}

// ============ setup5: fill_adj (packed pos+ts) ∥ x_scatter ============
__global__ __launch_bounds__(256) void setup5(
        const int* __restrict__ srcp, const int* __restrict__ dstp,
        const int* __restrict__ ts, const int* __restrict__ off,
        int* __restrict__ cursor, int2* __restrict__ adjst,
        const float* __restrict__ x, const int* __restrict__ pos,
        f16x4* __restrict__ x2p4) {
    int b = blockIdx.x, tid = threadIdx.x;
    if (b < CIB) {
        int e = b * 256 + tid;
        if (e < NE) {
            int d = dstp[e];
            int s2 = srcp[e];
            int p = atomicAdd(&cursor[d], 1);
            adjst[off[d] + p] = make_int2(s2, (ts[s2] << 25) | pos[s2]);
        }
    } else {
        int idx = (b - CIB) * 256 + tid;
        if (idx >= NN * 48) return;
        int i = idx / 48, cp4 = idx - i * 48;
        int c0 = cp4 * 4;
        float v0 = 0.f, v1 = 0.f, v2 = 0.f, v3 = 0.f;
        const float* xr = x + (size_t)i * FF;
        if (c0 + 3 < FF) {
            float2 p0 = *(const float2*)(xr + c0);
            float2 p1 = *(const float2*)(xr + c0 + 2);
            v0 = p0.x; v1 = p0.y; v2 = p1.x; v3 = p1.y;
        } else if (c0 < FF) {   // c0 == 164
            float2 p0 = *(const float2*)(xr + c0);
            v0 = p0.x; v1 = p0.y;
        }
        f16x4 h;
        h[0] = (_Float16)v0; h[1] = (_Float16)v1;
        h[2] = (_Float16)v2; h[3] = (_Float16)v3;
        x2p4[(size_t)pos[i] * 48 + cp4] = h;
    }
}

// ============ degf_m: degf_hist ∥ m_build (256 thr) ============
__global__ __launch_bounds__(256) void degf_m(
        const int* __restrict__ off, const int2* __restrict__ adjst,
        const int* __restrict__ ts, _Float16* __restrict__ dinvh,
        float* __restrict__ selfdeg,
        const float* __restrict__ W_all, const float* __restrict__ projwT,
        _Float16* __restrict__ Mh) {
    __shared__ unsigned short sh[TT * 256];
    __shared__ __align__(16) float sw2[2][168];
    int b = blockIdx.x;
    int tid = threadIdx.x;
    if (b < DEGB) {
        int i = b * 256 + tid;
        for (int t = 0; t < TT; ++t) sh[t * 256 + tid] = 0;
        if (i >= NN) return;
        int tsi = ts[i];
        int e0 = off[i], e1 = off[i + 1];
        for (int e = e0; e < e1; ++e) {
            int tj = adjst[e].y >> 25;
            sh[tj * 256 + tid]++;
        }
        int cum = 1;
        for (int t = 0; t < TT; ++t) {
            cum += sh[t * 256 + tid];
            dinvh[(size_t)t * NN + i] = (_Float16)rsqrtf((float)cum);
            if (t == tsi) selfdeg[i] = 1.0f / (float)cum;
        }
    } else {
        int mb = b - DEGB;                 // 0..4703
        int t = mb / 96, rb = mb - t * 96; // rows r0 = rb*2 (0..190)
        int r0 = rb * 2;
        for (int idx = tid; idx < 2 * FF; idx += 256) {
            int rr = idx / FF, k = idx - rr * FF;
            int r = r0 + rr;
            sw2[rr][k] = (r < FF) ? W_all[((size_t)t * FF + r) * FF + k] : 0.0f;
        }
        __syncthreads();
        int rr = tid >> 7, h = tid & 127;
        int r = r0 + rr;
        float acc = 0.0f;
        if (r < FF) {
            const float* __restrict__ pw = projwT + h;
            #pragma unroll 4
            for (int c4 = 0; c4 < 164; c4 += 4) {
                float4 w = *(const float4*)&sw2[rr][c4];
                acc += w.x * pw[(size_t)(c4 + 0) << 7];
                acc += w.y * pw[(size_t)(c4 + 1) << 7];
                acc += w.z * pw[(size_t)(c4 + 2) << 7];
                acc += w.w * pw[(size_t)(c4 + 3) << 7];
            }
            acc += sw2[rr][164] * pw[(size_t)164 << 7];
            acc += sw2[rr][165] * pw[(size_t)165 << 7];
        }
        Mh[((size_t)t * HH + h) * KPAD + r] = (_Float16)acc;
    }
}

// ============ edge_compact: ewp[off[i]..] = {pos_j, w>0} (pos pre-packed) ============
__global__ __launch_bounds__(256) void edge_compact(
        const int* __restrict__ off, const int2* __restrict__ adjst,
        const int* __restrict__ ts, const _Float16* __restrict__ dinvh,
        int2* __restrict__ ewp, int* __restrict__ nact) {
    int i = blockIdx.x * 256 + threadIdx.x;
    if (i >= NN) return;
    int t = ts[i];
    const _Float16* dv = dinvh + (size_t)t * NN;
    float dvi = (float)dv[i];
    int e0 = off[i], e1 = off[i + 1];
    int c = e0;
    for (int e = e0; e < e1; ++e) {
        int2 a = adjst[e];
        if ((a.y >> 25) <= t) {
            float w = (float)dv[a.x] * dvi;
            ewp[c++] = make_int2(a.y & 0x1FFFFFF, __float_as_int(w));
        }
    }
    nact[i] = c - e0;
}

// ============ fused: staged self + pipelined 4-row/wave edge gather + MFMA + proj + cls ============
__global__ __launch_bounds__(512) void gemm_fused5(
        const int* __restrict__ meta, const int* __restrict__ tile_t,
        const int* __restrict__ tile_r0, const int* __restrict__ perm,
        const float* __restrict__ selfdeg, const f16x4* __restrict__ x2p4,
        const int* __restrict__ off, const int* __restrict__ nact,
        const int2* __restrict__ ewp,
        const _Float16* __restrict__ Mh, const float* __restrict__ proj_b,
        const float* __restrict__ cls_w, const float* __restrict__ cls_b,
        float* __restrict__ out) {
    __shared__ __align__(16) char smraw[32 * 130 * 4];
    _Float16* sY = (_Float16*)smraw;   // [32][200] fp16
    float* sP = (float*)smraw;         // [32][130] f32
    int bid = blockIdx.x;
    if (bid >= meta[0]) return;
    int t = tile_t[bid], r0 = tile_r0[bid];
    int tid = threadIdx.x;
    int lane = tid & 63;
    int w = tid >> 6;          // 8 waves
    bool ln48 = lane < 48;

    // ---- stage x2p tile (32 contiguous rows x 24 uint4 = 12 KB) ----
    {
        const uint4* src = (const uint4*)(x2p4 + (size_t)r0 * 48);
        #pragma unroll
        for (int u = 0; u < 2; ++u) {
            int q = tid + u * 512;
            if (q < 768) {
                int row = q / 24, kc = q - row * 24;
                *(uint4*)(sY + row * 200 + kc * 8) = src[q];
            }
        }
    }
    __syncthreads();

    // ---- phase 0: wave w owns rows w*4..w*4+3; pipelined ewp + 8B/lane gathers ----
    int rbase = w * 4;
    int ep[4], ee[4];
    float ac[4][4];
    #pragma unroll
    for (int q = 0; q < 4; ++q) {
        int r = rbase + q;
        int i = perm[r0 + r];
        float sw = 0.0f;
        ep[q] = 0; ee[q] = 0;
        if (i >= 0) {
            sw = selfdeg[i];
            ep[q] = off[i];
            ee[q] = ep[q] + nact[i];
        }
        f16x4 h = (f16x4)((_Float16)0.0f);
        if (ln48) h = *(const f16x4*)(sY + r * 200 + lane * 4);
        ac[q][0] = sw * (float)h[0];
        ac[q][1] = sw * (float)h[1];
        ac[q][2] = sw * (float)h[2];
        ac[q][3] = sw * (float)h[3];
    }
    int2 pc[4];
    #pragma unroll
    for (int q = 0; q < 4; ++q) pc[q] = (ep[q] < ee[q]) ? ewp[ep[q]] : make_int2(0, 0);
    while ((ep[0] < ee[0]) | (ep[1] < ee[1]) | (ep[2] < ee[2]) | (ep[3] < ee[3])) {
        int js[4]; float wv[4];
        #pragma unroll
        for (int q = 0; q < 4; ++q) {
            bool val = ep[q] < ee[q];
            js[q] = pc[q].x;
            wv[q] = val ? __int_as_float(pc[q].y) : 0.0f;
            if (val) ep[q]++;
        }
        #pragma unroll
        for (int q = 0; q < 4; ++q) pc[q] = (ep[q] < ee[q]) ? ewp[ep[q]] : make_int2(0, 0);
        #pragma unroll
        for (int q = 0; q < 4; ++q) {
            if (wv[q] != 0.0f && ln48) {
                f16x4 g = x2p4[(size_t)js[q] * 48 + lane];
                ac[q][0] += wv[q] * (float)g[0];
                ac[q][1] += wv[q] * (float)g[1];
                ac[q][2] += wv[q] * (float)g[2];
                ac[q][3] += wv[q] * (float)g[3];
            }
        }
    }
    #pragma unroll
    for (int q = 0; q < 4; ++q) {
        if (ln48) {
            f16x4 o;
            o[0] = (_Float16)ac[q][0];
            o[1] = (_Float16)ac[q][1];
            o[2] = (_Float16)ac[q][2];
            o[3] = (_Float16)ac[q][3];
            *(f16x4*)(sY + (rbase + q) * 200 + lane * 4) = o;
        }
    }
    __syncthreads();

    // ---- phase 1: MFMA. wave w -> 16-col block c0 = w*16 ----
    int lr = lane & 15;
    int kg = lane >> 4;
    int c0 = w * 16;
    f32x4 acc0 = {0, 0, 0, 0}, acc1 = {0, 0, 0, 0};
    const _Float16* B0 = Mh + ((size_t)t * HH + c0 + lr) * KPAD + kg * 8;
    const _Float16* A0 = sY + lr * 200 + kg * 8;
    const _Float16* A1 = A0 + 16 * 200;

    #pragma unroll
    for (int s = 0; s < 6; ++s) {
        f16x8 b0 = *(const f16x8*)(B0 + s * 32);
        f16x8 a0 = *(const f16x8*)(A0 + s * 32);
        f16x8 a1 = *(const f16x8*)(A1 + s * 32);
        acc0 = __builtin_amdgcn_mfma_f32_16x16x32_f16(a0, b0, acc0, 0, 0, 0);
        acc1 = __builtin_amdgcn_mfma_f32_16x16x32_f16(a1, b0, acc1, 0, 0, 0);
    }

    float pb = proj_b[c0 + lr];
    __syncthreads();
    int prow = kg * 4;
    int colw = c0 + lr;
    #pragma unroll
    for (int r = 0; r < 4; ++r) {
        sP[(prow + r) * 130 + colw]      = fmaxf(acc0[r] + pb, 0.0f);
        sP[(16 + prow + r) * 130 + colw] = fmaxf(acc1[r] + pb, 0.0f);
    }
    __syncthreads();

    // ---- phase 2: logits ----
    int row = tid >> 4, cc = (tid >> 3) & 1, qq = tid & 7;
    const float* pr = sP + row * 130 + qq * 16;
    const float* cw = cls_w + cc * HH + qq * 16;
    float s = 0.0f;
    #pragma unroll
    for (int h = 0; h < 16; ++h) s += pr[h] * cw[h];
    s += __shfl_xor(s, 1);
    s += __shfl_xor(s, 2);
    s += __shfl_xor(s, 4);
    if (qq == 0) {
        int node = perm[r0 + row];
        if (node >= 0) out[(size_t)node * CC + cc] = s + cls_b[cc];
    }
}

// ============ host ============
extern "C" void kernel_launch(void* const* d_in, const int* in_sizes, int n_in,
                              void* d_out, int out_size, void* d_ws, size_t ws_size,
                              hipStream_t stream) {
    const float* x = (const float*)d_in[0];
    const int* ei = (const int*)d_in[1];
    const int* srcp = ei;
    const int* dstp = ei + NE;
    const int* ts = (const int*)d_in[2];
    const float* initial_w = (const float*)d_in[3];
    const float* wih = (const float*)d_in[4];
    const float* whh = (const float*)d_in[5];
    const float* bih = (const float*)d_in[6];
    const float* bhh = (const float*)d_in[7];
    const float* projw = (const float*)d_in[8];
    const float* projb = (const float*)d_in[9];
    const float* clsw = (const float*)d_in[10];
    const float* clsb = (const float*)d_in[11];
    float* out = (float*)d_out;

    char* base = (char*)d_ws;
    size_t o = 0;
    auto alloc = [&](size_t bytes) { size_t r = o; o = (o + bytes + 255) & ~(size_t)255; return r; };

    float*    W_all   = (float*)   (base + alloc((size_t)TT * FF * FF * 4));
    _Float16* Mh      = (_Float16*)(base + alloc((size_t)TT * HH * KPAD * 2));
    _Float16* wkp     = (_Float16*)(base + alloc((size_t)2 * KP * 512 * 2 * 2));
    float*    projwT  = (float*)   (base + alloc((size_t)FF * HH * 4));
    int*      off     = (int*)     (base + alloc((size_t)(NN + 1) * 4));
    int*      cursor  = (int*)     (base + alloc((size_t)NN * 4));
    int2*     adjst   = (int2*)    (base + alloc((size_t)NE * 8));
    int2*     ewp     = (int2*)    (base + alloc((size_t)NE * 8));
    _Float16* dinvh   = (_Float16*)(base + alloc((size_t)TT * NN * 2));
    float*    selfdeg = (float*)   (base + alloc((size_t)NN * 4));
    int*      nact    = (int*)     (base + alloc((size_t)NN * 4));
    int*      pos     = (int*)     (base + alloc((size_t)NN * 4));
    int*      bcnt    = (int*)     (base + alloc((size_t)TT * 4));
    int*      pstart  = (int*)     (base + alloc((size_t)(TT + 1) * 4));
    int*      meta    = (int*)     (base + alloc(2 * 4));
    int*      tile_t  = (int*)     (base + alloc((size_t)MAXTILES * 4));
    int*      tile_r0 = (int*)     (base + alloc((size_t)MAXTILES * 4));
    int*      perm    = (int*)     (base + alloc((size_t)PADN * 4));
    int*      bsum    = (int*)     (base + alloc((size_t)512 * 4));
    int*      bpre    = (int*)     (base + alloc((size_t)520 * 4));
    int*      cnt     = (int*)     (base + alloc((size_t)HB * TT * 4));
    int*      basecol = (int*)     (base + alloc((size_t)HB * TT * 4));
    int*      rank    = (int*)     (base + alloc((size_t)NN * 4));
    f16x4*    x2p4    = (f16x4*)   (base + alloc((size_t)PADN * 48 * 8));

    // off and cursor are adjacent: one memset covers both
    hipMemsetAsync(off, 0, (size_t)((char*)cursor - (char*)off) + (size_t)NN * 4, stream);
    hipMemsetAsync(perm, 0xFF, (size_t)PADN * 4, stream);

    setup1<<<P2B + C2B + H2B, 512, 0, stream>>>(wih, whh, projw, wkp, projwT,
                                                dstp, off, ts, cnt, rank);
    setup2g<<<FF + SNB + TT, 512, 0, stream>>>(initial_w, wkp, bih, bhh, W_all,
                                               off, bsum, cnt, basecol, bcnt);
    setup3<<<2, 512, 0, stream>>>(bsum, bpre, off, bcnt, pstart, tile_t, tile_r0, meta);
    setup4<<<SNB + SNB, 512, 0, stream>>>(off, bpre, ts, rank, basecol, pstart, perm, pos);
    setup5<<<CIB + XSB, 256, 0, stream>>>(srcp, dstp, ts, off, cursor, adjst, x, pos, x2p4);
    degf_m<<<DEGB + MBB, 256, 0, stream>>>(off, adjst, ts, dinvh, selfdeg, W_all, projwT, Mh);
    edge_compact<<<(NN + 255) / 256, 256, 0, stream>>>(off, adjst, ts, dinvh, ewp, nact);

    gemm_fused5<<<MAXTILES, 512, 0, stream>>>(meta, tile_t, tile_r0, perm, selfdeg,
                                              x2p4, off, nact, ewp, Mh, projb, clsw, clsb, out);
}

// Round 18
// 318.062 us; speedup vs baseline: 1.0558x; 1.0059x over previous
//
#include <hip/hip_runtime.h>
#include <hip/hip_fp16.h>
#include <math.h>

#define NN 200000
#define NE 500000
#define FF 166
#define HH 128
#define CC 2
#define TT 49
#define GG 498            // 3*FF
#define PADN 203136
#define MAXTILES 6400
#define KP 84             // k-pairs (166 -> 84 half2, padded)
#define KPAD 192          // K padded to 6*32 for MFMA
#define SCB 512           // scan elements per block
#define SNB 391           // ceil(NN/512)
#define HB 782            // 256-element histogram chunks
#define CIB 1954          // ceil(NE/256)
#define XSB 37500         // ceil(NN*48/256)
#define ECB 782           // edge_compact blocks
// setup1 (512-thread) block ranges
#define P2B 210           // ceil((2*KP*512 + FF*HH)/512)
#define C2B 977           // ceil(NE/512)
#define H2B 391           // ceil(NN/512) hist chunks
// degf_m ranges
#define DEGB 782
#define MBB (TT * 96)     // 4704: 2 rows/block covering KPAD=192 rows

typedef _Float16 half2v __attribute__((ext_vector_type(2)));
typedef _Float16 f16x4 __attribute__((ext_vector_type(4)));
typedef _Float16 f16x8 __attribute__((ext_vector_type(8)));
typedef float f32x4 __attribute__((ext_vector_type(4)));
typedef unsigned long long u64;

static __device__ __forceinline__ float fdot2f(half2v a, half2v b, float c) {
#if __has_builtin(__builtin_amdgcn_fdot2)
    return __builtin_amdgcn_fdot2(a, b, c, false);
#else
    return c + (float)a.x * (float)b.x + (float)a.y * (float)b.y;
#endif
}

// ============ setup1: prep_pack ∥ count_indeg ∥ hist_rank ============
__global__ __launch_bounds__(512) void setup1(
        const float* __restrict__ wih, const float* __restrict__ whh,
        const float* __restrict__ projw,
        _Float16* __restrict__ wkp, float* __restrict__ projwT,
        const int* __restrict__ dstp, int* __restrict__ offc,
        const int* __restrict__ ts, int* __restrict__ cnt, int* __restrict__ rank) {
    __shared__ int h2[2][TT];
    int b = blockIdx.x;
    int tid = threadIdx.x;
    if (b < P2B) {
        int idx = b * 512 + tid;
        const int A = 2 * KP * 512;
        if (idx < A) {
            int m = idx / (KP * 512);
            int r = idx - m * (KP * 512);
            int kp = r >> 9, c = r & 511;
            const float* Wm = m ? whh : wih;
            float x0 = 0.0f, x1 = 0.0f;
            if (c < GG) {
                int k0 = 2 * kp, k1 = 2 * kp + 1;
                if (k0 < FF) x0 = Wm[c * FF + k0];
                if (k1 < FF) x1 = Wm[c * FF + k1];
            }
            wkp[2 * idx]     = (_Float16)x0;
            wkp[2 * idx + 1] = (_Float16)x1;
        } else if (idx < A + FF * HH) {
            int q = idx - A;
            int k = q >> 7, hh = q & 127;
            projwT[q] = projw[hh * FF + k];
        }
    } else if (b < P2B + C2B) {
        int e = (b - P2B) * 512 + tid;
        if (e < NE) atomicAdd(&offc[dstp[e]], 1);
    } else {
        int hb2 = b - P2B - C2B;                  // 0..390
        int sub = tid >> 8;                       // 0/1
        int lt = tid & 255;
        if (lt < TT) h2[sub][lt] = 0;
        __syncthreads();
        int i = hb2 * 512 + tid;
        if (i < NN) {
            int t = ts[i];
            rank[i] = atomicAdd(&h2[sub][t], 1);
        }
        __syncthreads();
        if (lt < TT) cnt[(hb2 * 2 + sub) * TT + lt] = h2[sub][lt];
    }
}

// ============ setup2g: gru_evolve (166) ∥ scan_p1 (391) ∥ bucket_scan (49) ============
__global__ __launch_bounds__(512) void setup2g(
        const float* __restrict__ initial_w, const _Float16* __restrict__ wkp,
        const float* __restrict__ bih, const float* __restrict__ bhh,
        float* __restrict__ W_all,
        const int* __restrict__ off, int* __restrict__ bsum,
        const int* __restrict__ cnt, int* __restrict__ basecol, int* __restrict__ bcnt) {
    __shared__ float s_w[FF];
    __shared__ __align__(16) _Float16 s_wh[2 * KP];
    __shared__ float s_pre[2][512];
    __shared__ int s[512];
    int tid = threadIdx.x;
    int b = blockIdx.x;

    if (b < FF) {
        int row = b;
        if (tid < FF) {
            float v = initial_w[(size_t)row * FF + tid];
            s_w[tid] = v;
            s_wh[tid] = (_Float16)v;
        } else if (tid < 2 * KP) {
            s_wh[tid] = (_Float16)0.0f;
        }
        int cc0 = tid * 2;
        bool act = cc0 < 996;
        int m = (cc0 >= 498) ? 1 : 0;
        int c0 = act ? (cc0 - m * 498) : 0;
        half2v wr0[KP], wr1[KP];
        {
            const half2v* __restrict__ pW =
                (const half2v*)wkp + (size_t)(act ? m : 0) * (KP * 512) + c0;
            #pragma unroll
            for (int kp = 0; kp < KP; ++kp) {
                wr0[kp] = pW[(size_t)(kp << 9)];
                wr1[kp] = pW[(size_t)(kp << 9) + 1];
            }
        }
        float bi_r = 0, bi_z = 0, bi_n = 0, bh_r = 0, bh_z = 0, bh_n = 0;
        if (tid < FF) {
            bi_r = bih[tid]; bi_z = bih[FF + tid]; bi_n = bih[2 * FF + tid];
            bh_r = bhh[tid]; bh_z = bhh[FF + tid]; bh_n = bhh[2 * FF + tid];
        }
        __syncthreads();
        const f16x8* s_wh8 = (const f16x8*)s_wh;
        for (int t = 0; t < TT; ++t) {
            if (act) {
                float a0 = 0.0f, a1 = 0.0f;
                #pragma unroll
                for (int q = 0; q < 21; ++q) {
                    f16x8 w8 = s_wh8[q];
                    half2v h0 = __builtin_shufflevector(w8, w8, 0, 1);
                    half2v h1 = __builtin_shufflevector(w8, w8, 2, 3);
                    half2v h2v = __builtin_shufflevector(w8, w8, 4, 5);
                    half2v h3 = __builtin_shufflevector(w8, w8, 6, 7);
                    a0 = fdot2f(wr0[4 * q + 0], h0, a0);  a1 = fdot2f(wr1[4 * q + 0], h0, a1);
                    a0 = fdot2f(wr0[4 * q + 1], h1, a0);  a1 = fdot2f(wr1[4 * q + 1], h1, a1);
                    a0 = fdot2f(wr0[4 * q + 2], h2v, a0); a1 = fdot2f(wr1[4 * q + 2], h2v, a1);
                    a0 = fdot2f(wr0[4 * q + 3], h3, a0);  a1 = fdot2f(wr1[4 * q + 3], h3, a1);
                }
                s_pre[m][c0]     = a0;
                s_pre[m][c0 + 1] = a1;
            }
            __syncthreads();
            if (tid < FF) {
                float i_r = s_pre[0][tid]          + bi_r;
                float h_r = s_pre[1][tid]          + bh_r;
                float i_z = s_pre[0][FF + tid]     + bi_z;
                float h_z = s_pre[1][FF + tid]     + bh_z;
                float i_n = s_pre[0][2 * FF + tid] + bi_n;
                float h_n = s_pre[1][2 * FF + tid] + bh_n;
                float rg = 1.0f / (1.0f + expf(-(i_r + h_r)));
                float zg = 1.0f / (1.0f + expf(-(i_z + h_z)));
                float ng = tanhf(i_n + rg * h_n);
                float wnew = (1.0f - zg) * ng + zg * s_w[tid];
                s_w[tid] = wnew;
                s_wh[tid] = (_Float16)wnew;
                W_all[((size_t)t * FF + row) * FF + tid] = wnew;
            }
            __syncthreads();
        }
    } else if (b < FF + SNB) {
        int bb = b - FF;
        int i = bb * SCB + tid;
        s[tid] = (i < NN) ? off[i] : 0;
        __syncthreads();
        for (int d = 256; d > 0; d >>= 1) {
            if (tid < d) s[tid] += s[tid + d];
            __syncthreads();
        }
        if (tid == 0) bsum[bb] = s[0];
    } else {
        int t = b - FF - SNB;             // 0..48
        int b0 = tid * 2;
        int v0 = (b0 < HB) ? cnt[b0 * TT + t] : 0;
        int v1 = (b0 + 1 < HB) ? cnt[(b0 + 1) * TT + t] : 0;
        int sum = v0 + v1;
        s[tid] = sum;
        __syncthreads();
        for (int d = 1; d < 512; d <<= 1) {
            int u = (tid >= d) ? s[tid - d] : 0;
            __syncthreads();
            s[tid] += u;
            __syncthreads();
        }
        int base = s[tid] - sum;
        if (b0 < HB) basecol[b0 * TT + t] = base;
        if (b0 + 1 < HB) basecol[(b0 + 1) * TT + t] = base + v0;
        if (tid == 511) bcnt[t] = s[511];
    }
}

// ============ setup3: scan_p2 (block 0) ∥ make_tiles (block 1) ============
__global__ __launch_bounds__(512) void setup3(
        const int* __restrict__ bsum, int* __restrict__ bpre, int* __restrict__ off,
        const int* __restrict__ bcnt, int* __restrict__ pstart,
        int* __restrict__ tile_t, int* __restrict__ tile_r0, int* __restrict__ meta) {
    __shared__ int s[512];
    int tid = threadIdx.x;
    if (blockIdx.x == 0) {
        int v = (tid < SNB) ? bsum[tid] : 0;
        s[tid] = v;
        __syncthreads();
        for (int d = 1; d < 512; d <<= 1) {
            int u = (tid >= d) ? s[tid - d] : 0;
            __syncthreads();
            s[tid] += u;
            __syncthreads();
        }
        bpre[tid] = s[tid] - v;
        if (tid == 511) off[NN] = s[511];
    } else {
        int t = tid;
        int nt = (t < TT) ? (bcnt[t] + 31) / 32 : 0;
        if (t < 64) s[t] = nt;
        __syncthreads();
        for (int d = 1; d < 64; d <<= 1) {
            int v = (t >= d && t < 64) ? s[t - d] : 0;
            __syncthreads();
            if (t < 64) s[t] += v;
            __syncthreads();
        }
        if (t < 64) {
            int ntbase = s[t] - nt;
            int pbase = ntbase * 32;
            if (t < TT) {
                pstart[t] = pbase;
                for (int u = 0; u < nt; ++u) {
                    tile_t[ntbase + u] = t;
                    tile_r0[ntbase + u] = pbase + u * 32;
                }
            }
            if (t == 63) {
                meta[0] = s[63];
                meta[1] = s[63] * 32;
                pstart[TT] = s[63] * 32;
            }
        }
    }
}

// ============ setup4: scan_p3 ∥ perm_scatter ============
__global__ __launch_bounds__(512) void setup4(
        int* __restrict__ off, const int* __restrict__ bpre,
        const int* __restrict__ ts, const int* __restrict__ rank,
        const int* __restrict__ basecol, const int* __restrict__ pstart,
        int* __restrict__ perm, int* __restrict__ pos) {
    __shared__ int s[512];
    int b = blockIdx.x, tid = threadIdx.x;
    if (b < SNB) {
        int i = b * SCB + tid;
        int v = (i < NN) ? off[i] : 0;
        s[tid] = v;
        __syncthreads();
        for (int d = 1; d < 512; d <<= 1) {
            int u = (tid >= d) ? s[tid - d] : 0;
            __syncthreads();
            s[tid] += u;
            __syncthreads();
        }
        if (i < NN) off[i] = s[tid] - v + bpre[b];
    } else {
        int i = (b - SNB) * 512 + tid;
        if (i < NN) {
            int t = ts[i];
            int hb = i >> 8;
            int p = pstart[t] + basecol[hb * TT + t] + rank[i];
            perm[p] = i;
            pos[i] = p;
        }
    }
}

// ============ fill_adj (packed pos+ts) ============
__global__ __launch_bounds__(256) void fill_adj(
        const int* __restrict__ srcp, const int* __restrict__ dstp,
        const int* __restrict__ ts, const int* __restrict__ off,
        int* __restrict__ cursor, int2* __restrict__ adjst,
        const int* __restrict__ pos) {
    int e = blockIdx.x * 256 + threadIdx.x;
    if (e < NE) {
        int d = dstp[e];
        int s2 = srcp[e];
        int p = atomicAdd(&cursor[d], 1);
        adjst[off[d] + p] = make_int2(s2, (ts[s2] << 25) | pos[s2]);
    }
}

// ============ degf_m: degf_hist ∥ m_build (256 thr) ============
__global__ __launch_bounds__(256) void degf_m(
        const int* __restrict__ off, const int2* __restrict__ adjst,
        const int* __restrict__ ts, _Float16* __restrict__ dinvh,
        float* __restrict__ selfdeg,
        const float* __restrict__ W_all, const float* __restrict__ projwT,
        _Float16* __restrict__ Mh) {
    __shared__ unsigned short sh[TT * 256];
    __shared__ __align__(16) float sw2[2][168];
    int b = blockIdx.x;
    int tid = threadIdx.x;
    if (b < DEGB) {
        int i = b * 256 + tid;
        for (int t = 0; t < TT; ++t) sh[t * 256 + tid] = 0;
        if (i >= NN) return;
        int tsi = ts[i];
        int e0 = off[i], e1 = off[i + 1];
        for (int e = e0; e < e1; ++e) {
            int tj = adjst[e].y >> 25;
            sh[tj * 256 + tid]++;
        }
        int cum = 1;
        for (int t = 0; t < TT; ++t) {
            cum += sh[t * 256 + tid];
            dinvh[(size_t)t * NN + i] = (_Float16)rsqrtf((float)cum);
            if (t == tsi) selfdeg[i] = 1.0f / (float)cum;
        }
    } else {
        int mb = b - DEGB;                 // 0..4703
        int t = mb / 96, rb = mb - t * 96; // rows r0 = rb*2 (0..190)
        int r0 = rb * 2;
        for (int idx = tid; idx < 2 * FF; idx += 256) {
            int rr = idx / FF, k = idx - rr * FF;
            int r = r0 + rr;
            sw2[rr][k] = (r < FF) ? W_all[((size_t)t * FF + r) * FF + k] : 0.0f;
        }
        __syncthreads();
        int rr = tid >> 7, h = tid & 127;
        int r = r0 + rr;
        float acc = 0.0f;
        if (r < FF) {
            const float* __restrict__ pw = projwT + h;
            #pragma unroll 4
            for (int c4 = 0; c4 < 164; c4 += 4) {
                float4 w = *(const float4*)&sw2[rr][c4];
                acc += w.x * pw[(size_t)(c4 + 0) << 7];
                acc += w.y * pw[(size_t)(c4 + 1) << 7];
                acc += w.z * pw[(size_t)(c4 + 2) << 7];
                acc += w.w * pw[(size_t)(c4 + 3) << 7];
            }
            acc += sw2[rr][164] * pw[(size_t)164 << 7];
            acc += sw2[rr][165] * pw[(size_t)165 << 7];
        }
        Mh[((size_t)t * HH + h) * KPAD + r] = (_Float16)acc;
    }
}

// ============ setup6: edge_compact ∥ x_scatter (NT x reads; runs LAST before gemm) ============
__global__ __launch_bounds__(256) void setup6(
        const int* __restrict__ off, const int2* __restrict__ adjst,
        const int* __restrict__ ts, const _Float16* __restrict__ dinvh,
        int2* __restrict__ ewp, int* __restrict__ nact,
        const float* __restrict__ x, const int* __restrict__ pos,
        f16x4* __restrict__ x2p4) {
    int b = blockIdx.x, tid = threadIdx.x;
    if (b < ECB) {
        int i = b * 256 + tid;
        if (i >= NN) return;
        int t = ts[i];
        const _Float16* dv = dinvh + (size_t)t * NN;
        float dvi = (float)dv[i];
        int e0 = off[i], e1 = off[i + 1];
        int c = e0;
        for (int e = e0; e < e1; ++e) {
            int2 a = adjst[e];
            if ((a.y >> 25) <= t) {
                float w = (float)dv[a.x] * dvi;
                ewp[c++] = make_int2(a.y & 0x1FFFFFF, __float_as_int(w));
            }
        }
        nact[i] = c - e0;
    } else {
        int idx = (b - ECB) * 256 + tid;
        if (idx >= NN * 48) return;
        int i = idx / 48, cp4 = idx - i * 48;
        int c0 = cp4 * 4;
        const float* xr = x + (size_t)i * FF;
        union { u64 u; float f[2]; } p0, p1;
        p0.u = 0; p1.u = 0;
        if (c0 + 3 < FF) {
            p0.u = __builtin_nontemporal_load((const u64*)(xr + c0));
            p1.u = __builtin_nontemporal_load((const u64*)(xr + c0 + 2));
        } else if (c0 < FF) {   // c0 == 164
            p0.u = __builtin_nontemporal_load((const u64*)(xr + c0));
        }
        f16x4 h;
        h[0] = (_Float16)p0.f[0]; h[1] = (_Float16)p0.f[1];
        h[2] = (_Float16)p1.f[0]; h[3] = (_Float16)p1.f[1];
        x2p4[(size_t)pos[i] * 48 + cp4] = h;
    }
}

// ============ fused: staged self + pipelined 4-row/wave edge gather + MFMA + proj + cls ============
__global__ __launch_bounds__(512) void gemm_fused5(
        const int* __restrict__ meta, const int* __restrict__ tile_t,
        const int* __restrict__ tile_r0, const int* __restrict__ perm,
        const float* __restrict__ selfdeg, const f16x4* __restrict__ x2p4,
        const int* __restrict__ off, const int* __restrict__ nact,
        const int2* __restrict__ ewp,
        const _Float16* __restrict__ Mh, const float* __restrict__ proj_b,
        const float* __restrict__ cls_w, const float* __restrict__ cls_b,
        float* __restrict__ out) {
    __shared__ __align__(16) char smraw[32 * 130 * 4];
    _Float16* sY = (_Float16*)smraw;   // [32][200] fp16
    float* sP = (float*)smraw;         // [32][130] f32
    int bid = blockIdx.x;
    if (bid >= meta[0]) return;
    int t = tile_t[bid], r0 = tile_r0[bid];
    int tid = threadIdx.x;
    int lane = tid & 63;
    int w = tid >> 6;          // 8 waves
    bool ln48 = lane < 48;

    // ---- stage x2p tile (32 contiguous rows x 24 uint4 = 12 KB) ----
    {
        const uint4* src = (const uint4*)(x2p4 + (size_t)r0 * 48);
        #pragma unroll
        for (int u = 0; u < 2; ++u) {
            int q = tid + u * 512;
            if (q < 768) {
                int row = q / 24, kc = q - row * 24;
                *(uint4*)(sY + row * 200 + kc * 8) = src[q];
            }
        }
    }
    __syncthreads();

    // ---- phase 0: wave w owns rows w*4..w*4+3; pipelined ewp + 8B/lane gathers ----
    int rbase = w * 4;
    int ep[4], ee[4];
    float ac[4][4];
    #pragma unroll
    for (int q = 0; q < 4; ++q) {
        int r = rbase + q;
        int i = perm[r0 + r];
        float sw = 0.0f;
        ep[q] = 0; ee[q] = 0;
        if (i >= 0) {
            sw = selfdeg[i];
            ep[q] = off[i];
            ee[q] = ep[q] + nact[i];
        }
        f16x4 h = (f16x4)((_Float16)0.0f);
        if (ln48) h = *(const f16x4*)(sY + r * 200 + lane * 4);
        ac[q][0] = sw * (float)h[0];
        ac[q][1] = sw * (float)h[1];
        ac[q][2] = sw * (float)h[2];
        ac[q][3] = sw * (float)h[3];
    }
    int2 pc[4];
    #pragma unroll
    for (int q = 0; q < 4; ++q) pc[q] = (ep[q] < ee[q]) ? ewp[ep[q]] : make_int2(0, 0);
    while ((ep[0] < ee[0]) | (ep[1] < ee[1]) | (ep[2] < ee[2]) | (ep[3] < ee[3])) {
        int js[4]; float wv[4];
        #pragma unroll
        for (int q = 0; q < 4; ++q) {
            bool val = ep[q] < ee[q];
            js[q] = pc[q].x;
            wv[q] = val ? __int_as_float(pc[q].y) : 0.0f;
            if (val) ep[q]++;
        }
        #pragma unroll
        for (int q = 0; q < 4; ++q) pc[q] = (ep[q] < ee[q]) ? ewp[ep[q]] : make_int2(0, 0);
        #pragma unroll
        for (int q = 0; q < 4; ++q) {
            if (wv[q] != 0.0f && ln48) {
                f16x4 g = x2p4[(size_t)js[q] * 48 + lane];
                ac[q][0] += wv[q] * (float)g[0];
                ac[q][1] += wv[q] * (float)g[1];
                ac[q][2] += wv[q] * (float)g[2];
                ac[q][3] += wv[q] * (float)g[3];
            }
        }
    }
    #pragma unroll
    for (int q = 0; q < 4; ++q) {
        if (ln48) {
            f16x4 o;
            o[0] = (_Float16)ac[q][0];
            o[1] = (_Float16)ac[q][1];
            o[2] = (_Float16)ac[q][2];
            o[3] = (_Float16)ac[q][3];
            *(f16x4*)(sY + (rbase + q) * 200 + lane * 4) = o;
        }
    }
    __syncthreads();

    // ---- phase 1: MFMA. wave w -> 16-col block c0 = w*16 ----
    int lr = lane & 15;
    int kg = lane >> 4;
    int c0 = w * 16;
    f32x4 acc0 = {0, 0, 0, 0}, acc1 = {0, 0, 0, 0};
    const _Float16* B0 = Mh + ((size_t)t * HH + c0 + lr) * KPAD + kg * 8;
    const _Float16* A0 = sY + lr * 200 + kg * 8;
    const _Float16* A1 = A0 + 16 * 200;

    #pragma unroll
    for (int s = 0; s < 6; ++s) {
        f16x8 b0 = *(const f16x8*)(B0 + s * 32);
        f16x8 a0 = *(const f16x8*)(A0 + s * 32);
        f16x8 a1 = *(const f16x8*)(A1 + s * 32);
        acc0 = __builtin_amdgcn_mfma_f32_16x16x32_f16(a0, b0, acc0, 0, 0, 0);
        acc1 = __builtin_amdgcn_mfma_f32_16x16x32_f16(a1, b0, acc1, 0, 0, 0);
    }

    float pb = proj_b[c0 + lr];
    __syncthreads();
    int prow = kg * 4;
    int colw = c0 + lr;
    #pragma unroll
    for (int r = 0; r < 4; ++r) {
        sP[(prow + r) * 130 + colw]      = fmaxf(acc0[r] + pb, 0.0f);
        sP[(16 + prow + r) * 130 + colw] = fmaxf(acc1[r] + pb, 0.0f);
    }
    __syncthreads();

    // ---- phase 2: logits ----
    int row = tid >> 4, cc = (tid >> 3) & 1, qq = tid & 7;
    const float* pr = sP + row * 130 + qq * 16;
    const float* cw = cls_w + cc * HH + qq * 16;
    float s = 0.0f;
    #pragma unroll
    for (int h = 0; h < 16; ++h) s += pr[h] * cw[h];
    s += __shfl_xor(s, 1);
    s += __shfl_xor(s, 2);
    s += __shfl_xor(s, 4);
    if (qq == 0) {
        int node = perm[r0 + row];
        if (node >= 0) out[(size_t)node * CC + cc] = s + cls_b[cc];
    }
}

// ============ host ============
extern "C" void kernel_launch(void* const* d_in, const int* in_sizes, int n_in,
                              void* d_out, int out_size, void* d_ws, size_t ws_size,
                              hipStream_t stream) {
    const float* x = (const float*)d_in[0];
    const int* ei = (const int*)d_in[1];
    const int* srcp = ei;
    const int* dstp = ei + NE;
    const int* ts = (const int*)d_in[2];
    const float* initial_w = (const float*)d_in[3];
    const float* wih = (const float*)d_in[4];
    const float* whh = (const float*)d_in[5];
    const float* bih = (const float*)d_in[6];
    const float* bhh = (const float*)d_in[7];
    const float* projw = (const float*)d_in[8];
    const float* projb = (const float*)d_in[9];
    const float* clsw = (const float*)d_in[10];
    const float* clsb = (const float*)d_in[11];
    float* out = (float*)d_out;

    char* base = (char*)d_ws;
    size_t o = 0;
    auto alloc = [&](size_t bytes) { size_t r = o; o = (o + bytes + 255) & ~(size_t)255; return r; };

    float*    W_all   = (float*)   (base + alloc((size_t)TT * FF * FF * 4));
    _Float16* Mh      = (_Float16*)(base + alloc((size_t)TT * HH * KPAD * 2));
    _Float16* wkp     = (_Float16*)(base + alloc((size_t)2 * KP * 512 * 2 * 2));
    float*    projwT  = (float*)   (base + alloc((size_t)FF * HH * 4));
    int*      off     = (int*)     (base + alloc((size_t)(NN + 1) * 4));
    int*      cursor  = (int*)     (base + alloc((size_t)NN * 4));
    int2*     adjst   = (int2*)    (base + alloc((size_t)NE * 8));
    int2*     ewp     = (int2*)    (base + alloc((size_t)NE * 8));
    _Float16* dinvh   = (_Float16*)(base + alloc((size_t)TT * NN * 2));
    float*    selfdeg = (float*)   (base + alloc((size_t)NN * 4));
    int*      nact    = (int*)     (base + alloc((size_t)NN * 4));
    int*      pos     = (int*)     (base + alloc((size_t)NN * 4));
    int*      bcnt    = (int*)     (base + alloc((size_t)TT * 4));
    int*      pstart  = (int*)     (base + alloc((size_t)(TT + 1) * 4));
    int*      meta    = (int*)     (base + alloc(2 * 4));
    int*      tile_t  = (int*)     (base + alloc((size_t)MAXTILES * 4));
    int*      tile_r0 = (int*)     (base + alloc((size_t)MAXTILES * 4));
    int*      perm    = (int*)     (base + alloc((size_t)PADN * 4));
    int*      bsum    = (int*)     (base + alloc((size_t)512 * 4));
    int*      bpre    = (int*)     (base + alloc((size_t)520 * 4));
    int*      cnt     = (int*)     (base + alloc((size_t)HB * TT * 4));
    int*      basecol = (int*)     (base + alloc((size_t)HB * TT * 4));
    int*      rank    = (int*)     (base + alloc((size_t)NN * 4));
    f16x4*    x2p4    = (f16x4*)   (base + alloc((size_t)PADN * 48 * 8));

    // off and cursor are adjacent: one memset covers both
    hipMemsetAsync(off, 0, (size_t)((char*)cursor - (char*)off) + (size_t)NN * 4, stream);
    hipMemsetAsync(perm, 0xFF, (size_t)PADN * 4, stream);

    setup1<<<P2B + C2B + H2B, 512, 0, stream>>>(wih, whh, projw, wkp, projwT,
                                                dstp, off, ts, cnt, rank);
    setup2g<<<FF + SNB + TT, 512, 0, stream>>>(initial_w, wkp, bih, bhh, W_all,
                                               off, bsum, cnt, basecol, bcnt);
    setup3<<<2, 512, 0, stream>>>(bsum, bpre, off, bcnt, pstart, tile_t, tile_r0, meta);
    setup4<<<SNB + SNB, 512, 0, stream>>>(off, bpre, ts, rank, basecol, pstart, perm, pos);
    fill_adj<<<CIB, 256, 0, stream>>>(srcp, dstp, ts, off, cursor, adjst, pos);
    degf_m<<<DEGB + MBB, 256, 0, stream>>>(off, adjst, ts, dinvh, selfdeg, W_all, projwT, Mh);
    setup6<<<ECB + XSB, 256, 0, stream>>>(off, adjst, ts, dinvh, ewp, nact, x, pos, x2p4);

    gemm_fused5<<<MAXTILES, 512, 0, stream>>>(meta, tile_t, tile_r0, perm, selfdeg,
                                              x2p4, off, nact, ewp, Mh, projb, clsw, clsb, out);
}